// Round 13
// baseline (97.385 us; speedup 1.0000x reference)
//
#include <hip/hip_runtime.h>
#include <hip/hip_bf16.h>
#include <math.h>

// NTXent loss, N=8192 rows, D=128.
// loss = mean_i [ log(sum_{j!=i} exp(2*cos_ij)) - 2*cos_{i,partner} ]
// R21: MEASUREMENT ROUND. Three different LDS-staged sims (R13/R14/R20)
// all land at total ~81 with sim hidden below the harness's 41us poison
// fills -- sim's true duration and counters have never been observed for a
// clean (non-spilled) build. This round runs R20's sim with TWO passes in
// one dispatch (grid 1024; pass=bid>>9; pass 1 writes to scratch part2):
// the ~2x-duration dispatch ranks above the fills => full PMC (MfmaUtil,
// occupancy, bank conflicts, spill tripwire), and T21-T20 = S exactly.
// Decision rule: conflicts high -> fix swizzle; clean but occupancy-bound
// -> 64-row/wave restructure; if T21-T20 small -> gaps dominate -> fuse.

typedef __attribute__((ext_vector_type(8))) short bf16x8;   // 8 bf16 = 4 VGPRs
typedef __attribute__((ext_vector_type(4))) float f32x4;

#define NROWS 8192
#define DDIM  128
#define BHALF 4096
#define NCG   8                     // col groups
#define CGSZ  1024                  // cols per group
#define CHUNKC 128                  // cols per chunk (32 KB)
// zn scaled by sqrt(2/ln2): acc = (2/ln2)*cos, exp(2cos) = exp2(acc)
#define SQRT_E2S 1.6986435980707531f
#define LN2      0.6931471805599453f
#define EXPDIAG  7.38905609893065f

static __device__ __forceinline__ unsigned short f2bf(float f) {
  unsigned int u = __float_as_uint(f);
  unsigned int r = (u + 0x7fffu + ((u >> 16) & 1u)) >> 16;   // RNE
  return (unsigned short)r;
}

static __device__ __forceinline__ void glds16(const unsigned short* g, unsigned short* l) {
  __builtin_amdgcn_global_load_lds((const __attribute__((address_space(1))) unsigned int*)g,
                                   (__attribute__((address_space(3))) unsigned int*)l,
                                   16, 0, 0);
}

// ---- Kernel 1: normalize (scaled) + fp32 pair-dots + zero out ------------
// Block b: waves 0,1 -> rows 2b,2b+1 (zi); waves 2,3 -> their partners (zj).
__global__ void norm_kernel(const float* __restrict__ zi, const float* __restrict__ zj,
                            unsigned short* __restrict__ zn,
                            float* __restrict__ pos, float* __restrict__ out) {
  __shared__ float2 xbuf[2][64];
  int wave = threadIdx.x >> 6;
  int lane = threadIdx.x & 63;
  int pi   = blockIdx.x * 2 + (wave & 1);           // pair index
  int row  = pi + (wave >> 1) * BHALF;
  const float* src = (row < BHALF) ? (zi + (size_t)row * DDIM)
                                   : (zj + (size_t)(row - BHALF) * DDIM);
  float2 v = *(const float2*)(src + 2 * lane);
  float ss = v.x * v.x + v.y * v.y;
  #pragma unroll
  for (int off = 1; off < 64; off <<= 1) ss += __shfl_xor(ss, off);
  float scale = SQRT_E2S / fmaxf(sqrtf(ss), 1e-8f);
  v.x *= scale; v.y *= scale;
  unsigned int lo = f2bf(v.x), hi = f2bf(v.y);
  ((unsigned int*)(zn + (size_t)row * DDIM))[lane] = lo | (hi << 16);

  if (wave >= 2) xbuf[wave - 2][lane] = v;
  __syncthreads();
  if (wave < 2) {                                    // d = (2/ln2)*cos(i, i+B)
    float2 w = xbuf[wave][lane];
    float d = v.x * w.x + v.y * w.y;
    #pragma unroll
    for (int off = 1; off < 64; off <<= 1) d += __shfl_xor(d, off);
    if (lane == 0) pos[pi] = d;
  }
  if (blockIdx.x == 0 && threadIdx.x == 0) out[0] = 0.0f;
}

// ---- Kernel 2: full-matrix sim + exp + row partial sums (2 passes) -------
// Grid 1024: pass = bid>>9 (pass 1 = duplicate work to scratch for PMC
// visibility); within pass: strip = bid>>3 (128 rows), cg = bid&7 (1024
// cols). B staged 128 cols/chunk into 2x32KB LDS double buffer via glds;
// 8 phases, counted vmcnt, rolled loop. launch_bounds(256,2) (non-spill).
__global__ __launch_bounds__(256, 2)
void sim_kernel(const unsigned short* __restrict__ zn, float* __restrict__ part) {
  __shared__ unsigned short lds[2 * CHUNKC * DDIM];  // 64 KB

  const int w    = threadIdx.x >> 6;
  const int lane = threadIdx.x & 63;
  const int l15  = lane & 15;
  const int quad = lane >> 4;

  const int pass = blockIdx.x >> 9;
  const int bid  = blockIdx.x & 511;
  const int strip = bid >> 3;
  const int cg    = bid & 7;
  const int row_base = strip * 128 + w * 32;
  const int col0     = cg * CGSZ;
  float* pout = part + (size_t)pass * (NCG * NROWS);

  // A fragments: A[m=l15][k=quad*8+kf*32+j], 2 mi x 4 kf = 32 VGPR.
  // Issued FIRST (oldest in vmcnt order), pinned by sched_barrier.
  bf16x8 a[2][4];
  const unsigned short* abase = zn + (size_t)(row_base + l15) * DDIM + quad * 8;
  #pragma unroll
  for (int mi = 0; mi < 2; ++mi)
    #pragma unroll
    for (int kf = 0; kf < 4; ++kf)
      a[mi][kf] = *(const bf16x8*)(abase + mi * 16 * DDIM + kf * 32);
  __builtin_amdgcn_sched_barrier(0);   // pin: A-loads strictly before glds

  // Staging: chunk = 128 zn-rows (cols of sim). Wave w stages rows
  // w*32..w*32+31 via 8 glds16 (1 KB each: 4 rows). Slot layout XOR-
  // swizzled within each 256B row: slot s holds data chunk s^(r&15).
  const int rq = lane >> 4;            // row-within-4 for staging
  const int cl = lane & 15;            // 16B slot index

#define STAGE(CH, BUF)                                                         \
  {                                                                            \
    _Pragma("unroll")                                                          \
    for (int i = 0; i < 8; ++i) {                                              \
      int r = (w * 8 + i) * 4 + rq;                                            \
      int c = cl ^ (r & 15);                                                   \
      glds16(zn + (size_t)(col0 + (CH) * CHUNKC + r) * DDIM + c * 8,           \
             lds + (BUF) * (CHUNKC * DDIM) + (w * 8 + i) * 512);               \
    }                                                                          \
  }

  STAGE(0, 0)
  STAGE(1, 1)
  __builtin_amdgcn_sched_barrier(0);   // pin: glds issued before loop body

  int rdoff[4];
  #pragma unroll
  for (int kf = 0; kf < 4; ++kf)
    rdoff[kf] = l15 * DDIM + (((quad + 4 * kf) ^ l15) << 3);

  float rs[2][4];
  #pragma unroll
  for (int mi = 0; mi < 2; ++mi)
    #pragma unroll
    for (int r = 0; r < 4; ++r) rs[mi][r] = 0.0f;

#define COMPUTE(LB)                                                            \
  {                                                                            \
    _Pragma("unroll")                                                          \
    for (int ni = 0; ni < 8; ++ni) {                                           \
      bf16x8 b[4];                                                             \
      _Pragma("unroll")                                                        \
      for (int kf = 0; kf < 4; ++kf)                                           \
        b[kf] = *(const bf16x8*)((LB) + ni * 16 * DDIM + rdoff[kf]);           \
      f32x4 z = {0.0f, 0.0f, 0.0f, 0.0f};                                      \
      f32x4 acc0 = __builtin_amdgcn_mfma_f32_16x16x32_bf16(a[0][0], b[0], z, 0, 0, 0); \
      f32x4 acc1 = __builtin_amdgcn_mfma_f32_16x16x32_bf16(a[1][0], b[0], z, 0, 0, 0); \
      _Pragma("unroll")                                                        \
      for (int kf = 1; kf < 4; ++kf) {                                         \
        acc0 = __builtin_amdgcn_mfma_f32_16x16x32_bf16(a[0][kf], b[kf], acc0, 0, 0, 0); \
        acc1 = __builtin_amdgcn_mfma_f32_16x16x32_bf16(a[1][kf], b[kf], acc1, 0, 0, 0); \
      }                                                                        \
      _Pragma("unroll")                                                        \
      for (int r = 0; r < 4; ++r) {                                            \
        rs[0][r] += __builtin_amdgcn_exp2f(acc0[r]);                           \
        rs[1][r] += __builtin_amdgcn_exp2f(acc1[r]);                           \
      }                                                                        \
    }                                                                          \
  }

  // Phases 0..5: wait chunk ch (vmcnt(8): ch+1's 8 issues remain), compute,
  // barrier, restage buf with chunk ch+2.
  #pragma unroll 1
  for (int ch = 0; ch < 6; ++ch) {
    asm volatile("s_waitcnt vmcnt(8)" ::: "memory");
    __builtin_amdgcn_s_barrier();
    __builtin_amdgcn_sched_barrier(0);
    const unsigned short* lb = lds + (ch & 1) * (CHUNKC * DDIM);
    COMPUTE(lb)
    __builtin_amdgcn_sched_barrier(0);
    __builtin_amdgcn_s_barrier();
    STAGE(ch + 2, (ch & 1))
  }
  // Phase 6: chunk 6 in buf 0 (8 of chunk 7 still in flight).
  asm volatile("s_waitcnt vmcnt(8)" ::: "memory");
  __builtin_amdgcn_s_barrier();
  __builtin_amdgcn_sched_barrier(0);
  COMPUTE(lds)
  // Phase 7: chunk 7 in buf 1, drain all.
  asm volatile("s_waitcnt vmcnt(0)" ::: "memory");
  __builtin_amdgcn_s_barrier();
  __builtin_amdgcn_sched_barrier(0);
  COMPUTE(lds + CHUNKC * DDIM)
#undef COMPUTE
#undef STAGE

  // Row reduce across the 16 cols each l15 covers. C/D layout: col=l15,
  // row=quad*4+reg. Plain store to disjoint slot cg (per pass).
  #pragma unroll
  for (int mi = 0; mi < 2; ++mi)
    #pragma unroll
    for (int r = 0; r < 4; ++r) {
      float v = rs[mi][r];
      v += __shfl_xor(v, 1);
      v += __shfl_xor(v, 2);
      v += __shfl_xor(v, 4);
      v += __shfl_xor(v, 8);
      if (l15 == 0)
        pout[(size_t)cg * NROWS + row_base + mi * 16 + quad * 4 + r] = v;
    }
}

// ---- Kernel 3: sum 8 slots per row, logs + mean --------------------------
__global__ void finalize_kernel(const float* __restrict__ part,
                                const float* __restrict__ pos,
                                float* __restrict__ out) {
  __shared__ float red[4];
  int r = blockIdx.x * 256 + threadIdx.x;            // grid 32 x 256 = 8192 rows
  float s = 0.0f;
  #pragma unroll
  for (int k = 0; k < NCG; ++k) s += part[(size_t)k * NROWS + r];
  // per row: logsumexp(logits) - logits[0] = log(S - e^2) - ln2 * pos
  float v = logf(s - EXPDIAG) - LN2 * pos[r & (BHALF - 1)];
  #pragma unroll
  for (int off = 1; off < 64; off <<= 1) v += __shfl_xor(v, off);
  int wave = threadIdx.x >> 6, lane = threadIdx.x & 63;
  if (lane == 0) red[wave] = v;
  __syncthreads();
  if (threadIdx.x == 0)
    atomicAdd(out, (red[0] + red[1] + red[2] + red[3]) * (1.0f / 8192.0f));
}

extern "C" void kernel_launch(void* const* d_in, const int* in_sizes, int n_in,
                              void* d_out, int out_size, void* d_ws, size_t ws_size,
                              hipStream_t stream) {
  const float* zi = (const float*)d_in[0];
  const float* zj = (const float*)d_in[1];
  char* ws = (char*)d_ws;
  unsigned short* zn = (unsigned short*)ws;                       // 2 MB
  float* part = (float*)(ws + (size_t)NROWS * DDIM * 2);          // 2x256 KB (pass0|pass1)
  float* pos  = (float*)(ws + (size_t)NROWS * DDIM * 2
                            + 2 * (size_t)NCG * NROWS * 4);       // 16 KB
  float* out = (float*)d_out;

  norm_kernel<<<2048, 256, 0, stream>>>(zi, zj, zn, pos, out);
  sim_kernel<<<1024, 256, 0, stream>>>(zn, part);
  finalize_kernel<<<32, 256, 0, stream>>>(part, pos, out);
}